// Round 2
// baseline (407.105 us; speedup 1.0000x reference)
//
#include <hip/hip_runtime.h>
#include <cstdint>
#include <cstddef>

typedef __attribute__((ext_vector_type(8))) short short8;
typedef __attribute__((ext_vector_type(4))) float floatx4;

__device__ __forceinline__ unsigned short f2bf(float f) {
    unsigned int u = __builtin_bit_cast(unsigned int, f);
    u += 0x7fffu + ((u >> 16) & 1u);
    return (unsigned short)(u >> 16);
}
__device__ __forceinline__ float bflo(unsigned int u) {
    return __builtin_bit_cast(float, u << 16);
}
__device__ __forceinline__ short8 pack8(float4 a, float4 b) {
    short8 r;
    r[0] = (short)f2bf(a.x); r[1] = (short)f2bf(a.y);
    r[2] = (short)f2bf(a.z); r[3] = (short)f2bf(a.w);
    r[4] = (short)f2bf(b.x); r[5] = (short)f2bf(b.y);
    r[6] = (short)f2bf(b.z); r[7] = (short)f2bf(b.w);
    return r;
}

// ---------------------------------------------------------------------------
// gemm_batch: tile 64(M) x 128(N) x 32(K), block 256 = 4 waves, wave = 64x32.
// A staged in LDS (double-buffered, XOR-swizzled, 2-way free).
// B loaded DIRECTLY global->registers in MFMA fragment layout, two named
// register sets (X/Y) give a 2-K-step-deep prefetch (~800cy in flight).
// mode 1: NT, W f32 (N,K): per col, k is contiguous -> 4x float4 per step.
// mode 2: NN, W f32 (K,N): 16-lane col groups -> 16 dword (64B lines) per step.
// Output f32; split-K via atomicAdd (bias added by kz==0 only, or in LN).
// ---------------------------------------------------------------------------
struct SubGemm {
    const float* A; const float* W; const float* bias;
    float* Cf;
    int K, N, Kc, nj, ni, nkz, mode, ldc;
};
struct GemmBatch { SubGemm d[16]; int start[16]; int nd; };

#define MFMA_ALL() { _Pragma("unroll") for (int r_ = 0; r_ < 4; ++r_) { \
    acc[r_][0] = __builtin_amdgcn_mfma_f32_16x16x32_bf16(af[r_], bfr0, acc[r_][0], 0, 0, 0); \
    acc[r_][1] = __builtin_amdgcn_mfma_f32_16x16x32_bf16(af[r_], bfr1, acc[r_][1], 0, 0, 0); } }

#define READ_AF(buf) { _Pragma("unroll") for (int r_ = 0; r_ < 4; ++r_) \
    af[r_] = *(const short8*)&As[buf][aoff[r_]]; }

__global__ __launch_bounds__(256) void gemm_batch(GemmBatch gb)
{
    __shared__ short As[2][64 * 40];

    const int bx = blockIdx.x;
    int di = 0;
#pragma unroll 1
    for (int i = 1; i < gb.nd; ++i) if (bx >= gb.start[i]) di = i;
    const SubGemm g = gb.d[di];
    int local = bx - gb.start[di];
    const int jb = local % g.nj; local /= g.nj;
    const int ib = local % g.ni;
    const int kz = local / g.ni;

    const int tid = threadIdx.x;
    const int w = tid >> 6, lane = tid & 63;
    const int quad = lane >> 4, l16 = lane & 15;
    const int noff = w * 32;

    const int rA = tid >> 2;
    const int sAs = rA * 40 + (((tid & 3) ^ ((rA >> 3) & 3)) << 3);  // swizzled
    const float* pa = g.A + (size_t)(ib * 64 + rA) * g.K + kz * g.Kc + (tid & 3) * 8;

    int aoff[4];
#pragma unroll
    for (int r = 0; r < 4; ++r) {
        int row = r * 16 + l16;
        aoff[r] = row * 40 + ((quad ^ ((row >> 3) & 3)) << 3);
    }

    floatx4 acc[4][2] = {};
    const int steps = g.Kc >> 5;   // always even (Kc multiple of 64)
    short8 af[4], bfr0, bfr1;

    if (g.mode == 1) {
        const float* q0 = g.W + (size_t)(jb * 128 + noff + l16) * g.K + kz * g.Kc + quad * 8;
        const float* q1 = q0 + (size_t)16 * g.K;
        float4 xa0, xa1, ya0, ya1;
        float4 xb0, xb1, xb2, xb3, yb0, yb1, yb2, yb3;
        xa0 = *(const float4*)pa;        xa1 = *(const float4*)(pa + 4);
        xb0 = *(const float4*)q0;        xb1 = *(const float4*)(q0 + 4);
        xb2 = *(const float4*)q1;        xb3 = *(const float4*)(q1 + 4);
        pa += 32; q0 += 32; q1 += 32;
        ya0 = *(const float4*)pa;        ya1 = *(const float4*)(pa + 4);
        yb0 = *(const float4*)q0;        yb1 = *(const float4*)(q0 + 4);
        yb2 = *(const float4*)q1;        yb3 = *(const float4*)(q1 + 4);
        pa += 32; q0 += 32; q1 += 32;
        *(short8*)&As[0][sAs] = pack8(xa0, xa1);
#pragma unroll 1
        for (int s = 0; s < steps; s += 2) {
            __syncthreads();
            READ_AF(0);
            bfr0 = pack8(xb0, xb1); bfr1 = pack8(xb2, xb3);
            MFMA_ALL();
            *(short8*)&As[1][sAs] = pack8(ya0, ya1);
            if (s + 2 < steps) {
                xa0 = *(const float4*)pa; xa1 = *(const float4*)(pa + 4);
                xb0 = *(const float4*)q0; xb1 = *(const float4*)(q0 + 4);
                xb2 = *(const float4*)q1; xb3 = *(const float4*)(q1 + 4);
                pa += 32; q0 += 32; q1 += 32;
            }
            __syncthreads();
            READ_AF(1);
            bfr0 = pack8(yb0, yb1); bfr1 = pack8(yb2, yb3);
            MFMA_ALL();
            if (s + 2 < steps) {
                *(short8*)&As[0][sAs] = pack8(xa0, xa1);
                if (s + 3 < steps) {
                    ya0 = *(const float4*)pa; ya1 = *(const float4*)(pa + 4);
                    yb0 = *(const float4*)q0; yb1 = *(const float4*)(q0 + 4);
                    yb2 = *(const float4*)q1; yb3 = *(const float4*)(q1 + 4);
                    pa += 32; q0 += 32; q1 += 32;
                }
            }
        }
    } else {
        const float* rp[8];
#pragma unroll
        for (int i = 0; i < 8; ++i)
            rp[i] = g.W + ((size_t)(kz * g.Kc) + quad * 8 + i) * g.N
                        + (jb * 128 + noff + l16);
        const size_t bstep = (size_t)32 * g.N;
        float xnb[16], ynb[16];
        float4 xa0, xa1, ya0, ya1;

#define LDB_X() { _Pragma("unroll") for (int i_ = 0; i_ < 8; ++i_) { \
        xnb[i_] = rp[i_][0]; xnb[8 + i_] = rp[i_][16]; rp[i_] += bstep; } }
#define LDB_Y() { _Pragma("unroll") for (int i_ = 0; i_ < 8; ++i_) { \
        ynb[i_] = rp[i_][0]; ynb[8 + i_] = rp[i_][16]; rp[i_] += bstep; } }
#define CVT_X() { _Pragma("unroll") for (int e_ = 0; e_ < 8; ++e_) { \
        bfr0[e_] = (short)f2bf(xnb[e_]); bfr1[e_] = (short)f2bf(xnb[8 + e_]); } }
#define CVT_Y() { _Pragma("unroll") for (int e_ = 0; e_ < 8; ++e_) { \
        bfr0[e_] = (short)f2bf(ynb[e_]); bfr1[e_] = (short)f2bf(ynb[8 + e_]); } }

        xa0 = *(const float4*)pa; xa1 = *(const float4*)(pa + 4); pa += 32;
        LDB_X();
        ya0 = *(const float4*)pa; ya1 = *(const float4*)(pa + 4); pa += 32;
        LDB_Y();
        *(short8*)&As[0][sAs] = pack8(xa0, xa1);
#pragma unroll 1
        for (int s = 0; s < steps; s += 2) {
            __syncthreads();
            READ_AF(0);
            CVT_X();
            MFMA_ALL();
            *(short8*)&As[1][sAs] = pack8(ya0, ya1);
            if (s + 2 < steps) {
                xa0 = *(const float4*)pa; xa1 = *(const float4*)(pa + 4); pa += 32;
                LDB_X();
            }
            __syncthreads();
            READ_AF(1);
            CVT_Y();
            MFMA_ALL();
            if (s + 2 < steps) {
                *(short8*)&As[0][sAs] = pack8(xa0, xa1);
                if (s + 3 < steps) {
                    ya0 = *(const float4*)pa; ya1 = *(const float4*)(pa + 4); pa += 32;
                    LDB_Y();
                }
            }
        }
    }

#pragma unroll
    for (int r = 0; r < 4; ++r)
#pragma unroll
        for (int c = 0; c < 2; ++c) {
            const int col = jb * 128 + noff + c * 16 + l16;
            const float bj = (g.bias != nullptr && kz == 0) ? g.bias[col] : 0.f;
#pragma unroll
            for (int q = 0; q < 4; ++q) {
                const int row = ib * 64 + r * 16 + quad * 4 + q;
                const float v = acc[r][c][q] + bj;
                if (g.nkz > 1) atomicAdd(&g.Cf[(size_t)row * g.ldc + col], v);
                else           g.Cf[(size_t)row * g.ldc + col] = v;
            }
        }
}

// ---------------------------------------------------------------------------
// gemm128: 128x128x32 tile for the big kv projections (NT, W f32 (N,K),
// bf16 out). 4 waves in 2x2, each 64x64 (acc 4x4). Both operands staged in
// LDS, double-buffered, one barrier per K-step, XOR swizzle (2-way, free).
// ---------------------------------------------------------------------------
struct Sub128 { const float* A; const float* W; const float* bias; unsigned short* C; int K, N, nj; };
struct Batch128 { Sub128 d[4]; int start[4]; int nd; };

__global__ __launch_bounds__(256) void gemm128(Batch128 gb)
{
    __shared__ short As[2][128 * 40];
    __shared__ short Bs[2][128 * 40];

    const int bx = blockIdx.x;
    int di = 0;
#pragma unroll 1
    for (int i = 1; i < gb.nd; ++i) if (bx >= gb.start[i]) di = i;
    const Sub128 g = gb.d[di];
    const int local = bx - gb.start[di];
    const int jb = local % g.nj, ib = local / g.nj;

    const int tid = threadIdx.x;
    const int w = tid >> 6, lane = tid & 63;
    const int quad = lane >> 4, l16 = lane & 15;
    const int wm = (w >> 1) * 64, wn = (w & 1) * 64;

    const int rS = tid >> 1;
    const int gi0 = (tid & 1) * 2;
    const int jsw = (rS >> 3) & 3;
    const int s1 = rS * 40 + ((gi0 ^ jsw) << 3);
    const int s2 = rS * 40 + (((gi0 + 1) ^ jsw) << 3);
    const float* pa = g.A + (size_t)(ib * 128 + rS) * g.K + (tid & 1) * 16;
    const float* pb = g.W + (size_t)(jb * 128 + rS) * g.K + (tid & 1) * 16;

    int aoff[4], boff[4];
#pragma unroll
    for (int r = 0; r < 4; ++r) {
        int rowA = wm + r * 16 + l16;
        aoff[r] = rowA * 40 + ((quad ^ ((rowA >> 3) & 3)) << 3);
        int rowB = wn + r * 16 + l16;
        boff[r] = rowB * 40 + ((quad ^ ((rowB >> 3) & 3)) << 3);
    }

    floatx4 acc[4][4] = {};
    float4 a0 = *(const float4*)pa,       a1 = *(const float4*)(pa + 4);
    float4 a2 = *(const float4*)(pa + 8), a3 = *(const float4*)(pa + 12);
    float4 b0 = *(const float4*)pb,       b1 = *(const float4*)(pb + 4);
    float4 b2 = *(const float4*)(pb + 8), b3 = *(const float4*)(pb + 12);
    *(short8*)&As[0][s1] = pack8(a0, a1);
    *(short8*)&As[0][s2] = pack8(a2, a3);
    *(short8*)&Bs[0][s1] = pack8(b0, b1);
    *(short8*)&Bs[0][s2] = pack8(b2, b3);
    if (g.K > 32) {
        pa += 32; pb += 32;
        a0 = *(const float4*)pa;       a1 = *(const float4*)(pa + 4);
        a2 = *(const float4*)(pa + 8); a3 = *(const float4*)(pa + 12);
        b0 = *(const float4*)pb;       b1 = *(const float4*)(pb + 4);
        b2 = *(const float4*)(pb + 8); b3 = *(const float4*)(pb + 12);
    }
    int cur = 0;
#pragma unroll 1
    for (int k0 = 0; k0 < g.K; k0 += 32) {
        __syncthreads();
        short8 af[4], bf[4];
#pragma unroll
        for (int r = 0; r < 4; ++r) {
            af[r] = *(const short8*)&As[cur][aoff[r]];
            bf[r] = *(const short8*)&Bs[cur][boff[r]];
        }
#pragma unroll
        for (int r = 0; r < 4; ++r)
#pragma unroll
            for (int c = 0; c < 4; ++c)
                acc[r][c] = __builtin_amdgcn_mfma_f32_16x16x32_bf16(af[r], bf[c], acc[r][c], 0, 0, 0);
        if (k0 + 32 < g.K) {
            short* An = As[cur ^ 1]; short* Bn = Bs[cur ^ 1];
            *(short8*)&An[s1] = pack8(a0, a1);
            *(short8*)&An[s2] = pack8(a2, a3);
            *(short8*)&Bn[s1] = pack8(b0, b1);
            *(short8*)&Bn[s2] = pack8(b2, b3);
            if (k0 + 64 < g.K) {
                pa += 32; pb += 32;
                a0 = *(const float4*)pa;       a1 = *(const float4*)(pa + 4);
                a2 = *(const float4*)(pa + 8); a3 = *(const float4*)(pa + 12);
                b0 = *(const float4*)pb;       b1 = *(const float4*)(pb + 4);
                b2 = *(const float4*)(pb + 8); b3 = *(const float4*)(pb + 12);
            }
        }
        cur ^= 1;
    }

#pragma unroll
    for (int r = 0; r < 4; ++r)
#pragma unroll
        for (int c = 0; c < 4; ++c) {
            const int col = jb * 128 + wn + c * 16 + l16;
            const float bj = g.bias[col];
#pragma unroll
            for (int q = 0; q < 4; ++q) {
                const int row = ib * 128 + wm + r * 16 + quad * 4 + q;
                g.C[(size_t)row * g.N + col] = f2bf(acc[r][c][q] + bj);
            }
        }
}

// ---------------------------------------------------------------------------
// qk_batch: S(64b x 128m tile) = 0.125 * Q_h @ K_h^T, all 28 heads batched.
// ---------------------------------------------------------------------------
__global__ __launch_bounds__(256) void qk_batch(
    const float* __restrict__ qp_t, const float* __restrict__ qp_p, const float* __restrict__ qp_c,
    const unsigned short* __restrict__ kv_t, const unsigned short* __restrict__ kv_p, const unsigned short* __restrict__ kv_c,
    float* __restrict__ S_t, float* __restrict__ S_p, float* __restrict__ S_c)
{
    __shared__ short As[64 * 72];
    __shared__ short Bs[128 * 72];
    const int hy = blockIdx.y;
    const float* qp; const unsigned short* kv; float* S; int d, h;
    if (hy < 4)       { qp = qp_t; kv = kv_t; S = S_t; d = 256;  h = hy; }
    else if (hy < 12) { qp = qp_p; kv = kv_p; S = S_p; d = 512;  h = hy - 4; }
    else              { qp = qp_c; kv = kv_c; S = S_c; d = 1024; h = hy - 12; }

    const int j0 = blockIdx.x * 128;
    const int tid = threadIdx.x;
    const int w = tid >> 6, lane = tid & 63;
    const int quad = lane >> 4, l16 = lane & 15;
    const int noff = w * 32;
    const int twoD = 2 * d;

    {
        const int b = tid >> 2, kc = (tid & 3) * 16;
        const float* ga = qp + (size_t)b * d + h * 64 + kc;
        float4 a0 = *(const float4*)(ga + 0), a1 = *(const float4*)(ga + 4);
        float4 a2 = *(const float4*)(ga + 8), a3 = *(const float4*)(ga + 12);
        *(short8*)&As[b * 72 + kc + 0] = pack8(a0, a1);
        *(short8*)&As[b * 72 + kc + 8] = pack8(a2, a3);
    }
    {
        const int m = tid >> 1, hf = (tid & 1) * 32;
        const unsigned short* gb = kv + (size_t)(j0 + m) * twoD + h * 64 + hf;
        uint4 b0 = *(const uint4*)(gb + 0),  b1 = *(const uint4*)(gb + 8);
        uint4 b2 = *(const uint4*)(gb + 16), b3 = *(const uint4*)(gb + 24);
        *(uint4*)&Bs[m * 72 + hf + 0]  = b0;
        *(uint4*)&Bs[m * 72 + hf + 8]  = b1;
        *(uint4*)&Bs[m * 72 + hf + 16] = b2;
        *(uint4*)&Bs[m * 72 + hf + 24] = b3;
    }
    __syncthreads();

    floatx4 acc[4][2] = {};
#pragma unroll
    for (int k0 = 0; k0 < 64; k0 += 32) {
        short8 af[4], bfr[2];
#pragma unroll
        for (int r = 0; r < 4; ++r)
            af[r] = *(const short8*)&As[(r * 16 + l16) * 72 + k0 + quad * 8];
#pragma unroll
        for (int c = 0; c < 2; ++c)
            bfr[c] = *(const short8*)&Bs[(noff + c * 16 + l16) * 72 + k0 + quad * 8];
#pragma unroll
        for (int r = 0; r < 4; ++r)
#pragma unroll
            for (int c = 0; c < 2; ++c)
                acc[r][c] = __builtin_amdgcn_mfma_f32_16x16x32_bf16(af[r], bfr[c], acc[r][c], 0, 0, 0);
    }
#pragma unroll
    for (int r = 0; r < 4; ++r)
#pragma unroll
        for (int c = 0; c < 2; ++c) {
            int col = j0 + noff + c * 16 + l16;
#pragma unroll
            for (int q = 0; q < 4; ++q) {
                int row = r * 16 + quad * 4 + q;
                S[((size_t)h * 64 + row) * 2048 + col] = acc[r][c][q] * 0.125f;
            }
        }
}

// ---------------------------------------------------------------------------
// softmax_pv_batch: per (head, b): softmax over S row, then P @ V_h.
// ---------------------------------------------------------------------------
__global__ __launch_bounds__(256) void softmax_pv_batch(
    const float* __restrict__ S_t, const float* __restrict__ S_p, const float* __restrict__ S_c,
    const unsigned short* __restrict__ kv_t, const unsigned short* __restrict__ kv_p, const unsigned short* __restrict__ kv_c,
    const uint8_t* __restrict__ mask,
    float* __restrict__ o_t, float* __restrict__ o_p, float* __restrict__ o_c)
{
    const int hy = blockIdx.x, b = blockIdx.y;
    const float* S; const unsigned short* kv; float* o; int d, h;
    if (hy < 4)       { S = S_t; kv = kv_t; o = o_t; d = 256;  h = hy; }
    else if (hy < 12) { S = S_p; kv = kv_p; o = o_p; d = 512;  h = hy - 4; }
    else              { S = S_c; kv = kv_c; o = o_c; d = 1024; h = hy - 12; }

    const int tid = threadIdx.x;
    __shared__ __align__(16) float sc[2048];
    __shared__ float red[4];
    __shared__ float part[4][64];
    __shared__ float s_max, s_sum;

    const float* Sr = S + ((size_t)h * 64 + b) * 2048;
    const uint8_t* mr = mask + (size_t)b * 2048;

    float lmax = -1e30f;
    for (int m = tid; m < 2048; m += 256) {
        float s = Sr[m];
        if (mr[m]) s = -1e9f;
        sc[m] = s;
        lmax = fmaxf(lmax, s);
    }
#pragma unroll
    for (int off = 32; off; off >>= 1) lmax = fmaxf(lmax, __shfl_down(lmax, off));
    if ((tid & 63) == 0) red[tid >> 6] = lmax;
    __syncthreads();
    if (tid == 0) s_max = fmaxf(fmaxf(red[0], red[1]), fmaxf(red[2], red[3]));
    __syncthreads();
    const float mx = s_max;

    float lsum = 0.f;
    for (int m = tid; m < 2048; m += 256) {
        float e = __expf(sc[m] - mx);
        sc[m] = e;
        lsum += e;
    }
#pragma unroll
    for (int off = 32; off; off >>= 1) lsum += __shfl_down(lsum, off);
    if ((tid & 63) == 0) red[tid >> 6] = lsum;
    __syncthreads();
    if (tid == 0) s_sum = red[0] + red[1] + red[2] + red[3];
    __syncthreads();

    const int lane = tid & 63, w = tid >> 6;
    const int twoD = 2 * d;
    const unsigned short* vcol = kv + d + h * 64 + lane;
    float acc = 0.f;
    const int m0 = w * 512;
#pragma unroll 1
    for (int m = m0; m < m0 + 512; m += 8) {
#pragma unroll
        for (int j = 0; j < 8; ++j)
            acc += sc[m + j] * bflo((unsigned int)vcol[(size_t)(m + j) * twoD]);
    }
    part[w][lane] = acc;
    __syncthreads();
    if (tid < 64) {
        float r = (part[0][tid] + part[1][tid] + part[2][tid] + part[3][tid]) / s_sum;
        o[(size_t)b * d + h * 64 + tid] = r;
    }
}

// ---------------------------------------------------------------------------
// layernorm in place; also adds the lift bias (lifts accumulate without it).
// ---------------------------------------------------------------------------
__global__ __launch_bounds__(256) void ln_kernel(
    float* __restrict__ x, const float* __restrict__ g, const float* __restrict__ bb,
    const float* __restrict__ blt, const float* __restrict__ blp, const float* __restrict__ blc)
{
    const int row = blockIdx.x;
    const int l = row & 15;
    const float* lb = (l < 4)  ? (blt + (size_t)l * 4096)
                    : (l < 12) ? (blp + (size_t)(l - 4) * 4096)
                               : (blc + (size_t)(l - 12) * 4096);
    float* xr = x + (size_t)row * 4096;
    const int tid = threadIdx.x;
    float v[16];
    float sum = 0.f, sumsq = 0.f;
#pragma unroll
    for (int i = 0; i < 16; ++i) {
        int e = tid + i * 256;
        v[i] = xr[e] + lb[e];
        sum += v[i];
        sumsq += v[i] * v[i];
    }
    __shared__ float rs[4], rq[4];
#pragma unroll
    for (int off = 32; off; off >>= 1) {
        sum += __shfl_down(sum, off);
        sumsq += __shfl_down(sumsq, off);
    }
    if ((tid & 63) == 0) { rs[tid >> 6] = sum; rq[tid >> 6] = sumsq; }
    __syncthreads();
    const float ts = rs[0] + rs[1] + rs[2] + rs[3];
    const float tq = rq[0] + rq[1] + rq[2] + rq[3];
    const float mu = ts * (1.f / 4096.f);
    const float var = tq * (1.f / 4096.f) - mu * mu;
    const float r = rsqrtf(var + 1e-5f);
#pragma unroll
    for (int i = 0; i < 16; ++i) {
        int e = tid + i * 256;
        xr[e] = (v[i] - mu) * r * g[e] + bb[e];
    }
}

// ---------------------------------------------------------------------------
static void addg(GemmBatch& G, int& tot,
                 const float* A, const float* W, const float* bias, float* Cf,
                 int K, int N, int Kc, int nj, int ni, int nkz, int mode, int ldc)
{
    SubGemm& s = G.d[G.nd];
    s.A = A; s.W = W; s.bias = bias; s.Cf = Cf;
    s.K = K; s.N = N; s.Kc = Kc; s.nj = nj; s.ni = ni; s.nkz = nkz;
    s.mode = mode; s.ldc = ldc;
    G.start[G.nd] = tot;
    tot += nj * ni * nkz;
    G.nd++;
}
static void add128(Batch128& G, int& tot,
                   const float* A, const float* W, const float* bias, unsigned short* C,
                   int K, int N, int nj, int ni)
{
    Sub128& s = G.d[G.nd];
    s.A = A; s.W = W; s.bias = bias; s.C = C; s.K = K; s.N = N; s.nj = nj;
    G.start[G.nd] = tot;
    tot += nj * ni;
    G.nd++;
}

extern "C" void kernel_launch(void* const* d_in, const int* in_sizes, int n_in,
                              void* d_out, int out_size, void* d_ws, size_t ws_size,
                              hipStream_t stream)
{
    const float*   hs     = (const float*)d_in[0];
    const float*   fib_t  = (const float*)d_in[1];
    const float*   fib_p  = (const float*)d_in[2];
    const float*   fib_c  = (const float*)d_in[3];
    const uint8_t* mask   = (const uint8_t*)d_in[4];
    const float* Wq_t   = (const float*)d_in[5];  const float* bq_t   = (const float*)d_in[6];
    const float* Wq_p   = (const float*)d_in[7];  const float* bq_p   = (const float*)d_in[8];
    const float* Wq_c   = (const float*)d_in[9];  const float* bq_c   = (const float*)d_in[10];
    const float* Wqkv_t = (const float*)d_in[11]; const float* bqkv_t = (const float*)d_in[12];
    const float* Wo_t   = (const float*)d_in[13]; const float* bo_t   = (const float*)d_in[14];
    const float* Wqkv_p = (const float*)d_in[15]; const float* bqkv_p = (const float*)d_in[16];
    const float* Wo_p   = (const float*)d_in[17]; const float* bo_p   = (const float*)d_in[18];
    const float* Wqkv_c = (const float*)d_in[19]; const float* bqkv_c = (const float*)d_in[20];
    const float* Wo_c   = (const float*)d_in[21]; const float* bo_c   = (const float*)d_in[22];
    const float* Wl_t   = (const float*)d_in[23]; const float* bl_t   = (const float*)d_in[24];
    const float* Wl_p   = (const float*)d_in[25]; const float* bl_p   = (const float*)d_in[26];
    const float* Wl_c   = (const float*)d_in[27]; const float* bl_c   = (const float*)d_in[28];
    const float* ln_g   = (const float*)d_in[29]; const float* ln_b   = (const float*)d_in[30];

    char* wsb = (char*)d_ws;
    float* q_t  = (float*)wsb; wsb += 64 * 256 * 4;
    float* q_p  = (float*)wsb; wsb += 64 * 512 * 4;
    float* q_c  = (float*)wsb; wsb += 64 * 1024 * 4;
    float* qp_t = (float*)wsb; wsb += 64 * 256 * 4;
    float* qp_p = (float*)wsb; wsb += 64 * 512 * 4;
    float* qp_c = (float*)wsb; wsb += 64 * 1024 * 4;
    float* po_t = (float*)wsb; wsb += 64 * 256 * 4;
    float* po_p = (float*)wsb; wsb += 64 * 512 * 4;
    float* po_c = (float*)wsb; wsb += 64 * 1024 * 4;
    size_t zbytes = (size_t)(wsb - (char*)d_ws);
    float* o_t  = (float*)wsb; wsb += 64 * 256 * 4;
    float* o_p  = (float*)wsb; wsb += 64 * 512 * 4;
    float* o_c  = (float*)wsb; wsb += 64 * 1024 * 4;
    unsigned short* kv_t = (unsigned short*)wsb; wsb += 2048 * 512 * 2;
    unsigned short* kv_p = (unsigned short*)wsb; wsb += 2048 * 1024 * 2;
    unsigned short* kv_c = (unsigned short*)wsb; wsb += 2048 * 2048 * 2;
    float* S_t = (float*)wsb; wsb += (size_t)4  * 64 * 2048 * 4;
    float* S_p = (float*)wsb; wsb += (size_t)8  * 64 * 2048 * 4;
    float* S_c = (float*)wsb; wsb += (size_t)16 * 64 * 2048 * 4;
    float* out = (float*)d_out;

    const dim3 blk(256);
    hipMemsetAsync(d_ws, 0, zbytes, stream);
    hipMemsetAsync(d_out, 0, (size_t)out_size, stream);   // lifts accumulate atomically

    // ---- launch 1: bundle query heads (split-K, streaming Wq)
    {
        GemmBatch G{}; int tot = 0; G.nd = 0;
        addg(G, tot, hs, Wq_c, bq_c, q_c, 4096, 1024, 256, 8, 1, 16, 1, 1024);
        addg(G, tot, hs, Wq_p, bq_p, q_p, 4096, 512,  256, 4, 1, 16, 1, 512);
        addg(G, tot, hs, Wq_t, bq_t, q_t, 4096, 256,  256, 2, 1, 16, 1, 256);
        gemm_batch<<<dim3(tot), blk, 0, stream>>>(G);
    }

    // ---- launch 2: kv projections, 128x128 tile (bf16 out)
    {
        Batch128 G{}; int tot = 0; G.nd = 0;
        add128(G, tot, fib_c, Wqkv_c + 1024 * 1024, bqkv_c + 1024, kv_c, 1024, 2048, 16, 16);
        add128(G, tot, fib_p, Wqkv_p + 512 * 512,   bqkv_p + 512,  kv_p, 512,  1024, 8,  16);
        add128(G, tot, fib_t, Wqkv_t + 256 * 256,   bqkv_t + 256,  kv_t, 256,  512,  4,  16);
        gemm128<<<dim3(tot), blk, 0, stream>>>(G);
    }

    // ---- launch 3: q in-proj
    {
        GemmBatch G{}; int tot = 0; G.nd = 0;
        addg(G, tot, q_c, Wqkv_c, bqkv_c, qp_c, 1024, 1024, 128, 8, 1, 8, 1, 1024);
        addg(G, tot, q_p, Wqkv_p, bqkv_p, qp_p, 512,  512,  64,  4, 1, 8, 1, 512);
        addg(G, tot, q_t, Wqkv_t, bqkv_t, qp_t, 256,  256,  64,  2, 1, 4, 1, 256);
        gemm_batch<<<dim3(tot), blk, 0, stream>>>(G);
    }

    // ---- launch 4/5: attention
    qk_batch<<<dim3(16, 28), blk, 0, stream>>>(qp_t, qp_p, qp_c, kv_t, kv_p, kv_c, S_t, S_p, S_c);
    softmax_pv_batch<<<dim3(28, 64), blk, 0, stream>>>(S_t, S_p, S_c, kv_t, kv_p, kv_c, mask, o_t, o_p, o_c);

    // ---- launch 6: out-proj
    {
        GemmBatch G{}; int tot = 0; G.nd = 0;
        addg(G, tot, o_c, Wo_c, bo_c, po_c, 1024, 1024, 128, 8, 1, 8, 1, 1024);
        addg(G, tot, o_p, Wo_p, bo_p, po_p, 512,  512,  64,  4, 1, 8, 1, 512);
        addg(G, tot, o_t, Wo_t, bo_t, po_t, 256,  256,  64,  2, 1, 4, 1, 256);
        gemm_batch<<<dim3(tot), blk, 0, stream>>>(G);
    }

    // ---- launch 7: lifts (mode 2: B direct-to-reg streaming, split-K atomic)
    {
        GemmBatch G{}; int tot = 0; G.nd = 0;
        for (int z = 0; z < 4; ++z)
            addg(G, tot, po_c, Wl_c + (size_t)z * 1024 * 4096, nullptr,
                 out + (size_t)(12 + z) * 4096, 1024, 4096, 256, 32, 1, 4, 2, 16 * 4096);
        for (int z = 0; z < 8; ++z)
            addg(G, tot, po_p, Wl_p + (size_t)z * 512 * 4096, nullptr,
                 out + (size_t)(4 + z) * 4096, 512, 4096, 256, 32, 1, 2, 2, 16 * 4096);
        for (int z = 0; z < 4; ++z)
            addg(G, tot, po_t, Wl_t + (size_t)z * 256 * 4096, nullptr,
                 out + (size_t)z * 4096, 256, 4096, 256, 32, 1, 1, 2, 16 * 4096);
        gemm_batch<<<dim3(tot), blk, 0, stream>>>(G);
    }

    // ---- launch 8: layernorm in place (+ lift bias)
    ln_kernel<<<dim3(1024), blk, 0, stream>>>(out, ln_g, ln_b, bl_t, bl_p, bl_c);
}

// Round 3
// 387.983 us; speedup vs baseline: 1.0493x; 1.0493x over previous
//
#include <hip/hip_runtime.h>
#include <cstdint>
#include <cstddef>

typedef __attribute__((ext_vector_type(8))) short short8;
typedef __attribute__((ext_vector_type(4))) float floatx4;

__device__ __forceinline__ unsigned short f2bf(float f) {
    unsigned int u = __builtin_bit_cast(unsigned int, f);
    u += 0x7fffu + ((u >> 16) & 1u);
    return (unsigned short)(u >> 16);
}
__device__ __forceinline__ short8 pack8(float4 a, float4 b) {
    short8 r;
    r[0] = (short)f2bf(a.x); r[1] = (short)f2bf(a.y);
    r[2] = (short)f2bf(a.z); r[3] = (short)f2bf(a.w);
    r[4] = (short)f2bf(b.x); r[5] = (short)f2bf(b.y);
    r[6] = (short)f2bf(b.z); r[7] = (short)f2bf(b.w);
    return r;
}

// ---------------------------------------------------------------------------
// wave_gemm: ONE WAVE per block, tile 64(M) x 32(N), NO LDS, NO BARRIERS.
// M=64 fits a single wave's MFMA fragments, so the whole K-loop runs with a
// 2-deep named-register (X/Y) pipeline that the compiler can cover with
// counted vmcnt — no __syncthreads() to drain the load queue (the round-2
// failure: barrier drains killed every prefetch, ~5000cy per K-step).
// mode 0 (NT): W f32 (N,K) row-major, k contiguous  (qheads/inproj/outproj)
// mode 1 (NN): W f32 (K,N) k-major, ldw = row stride (lifts)
// Split-K via atomicAdd when nkz>1 (dest pre-zeroed); bias added at kz==0.
// ---------------------------------------------------------------------------
struct WaveG {
    const float* A; const float* W; const float* bias; float* C;
    int K, Kc, ldw, ldc, nj, nkz, mode;
};
struct WaveBatch { WaveG d[16]; int start[16]; int nd; };

#define MFMA_ALL() { _Pragma("unroll") for (int r_ = 0; r_ < 4; ++r_) { \
    acc[r_][0] = __builtin_amdgcn_mfma_f32_16x16x32_bf16(af[r_], bfr0, acc[r_][0], 0, 0, 0); \
    acc[r_][1] = __builtin_amdgcn_mfma_f32_16x16x32_bf16(af[r_], bfr1, acc[r_][1], 0, 0, 0); } }

#define LOADA(dst) { _Pragma("unroll") for (int r_ = 0; r_ < 4; ++r_) { \
    dst[r_][0] = *(const float4*)pa[r_]; dst[r_][1] = *(const float4*)(pa[r_] + 4); \
    pa[r_] += 32; } }

#define PACKA(src) { _Pragma("unroll") for (int r_ = 0; r_ < 4; ++r_) \
    af[r_] = pack8(src[r_][0], src[r_][1]); }

__global__ __launch_bounds__(64) void wave_gemm(WaveBatch wb)
{
    const int bx = blockIdx.x;
    int di = 0;
#pragma unroll 1
    for (int i = 1; i < wb.nd; ++i) if (bx >= wb.start[i]) di = i;
    const WaveG g = wb.d[di];
    int local = bx - wb.start[di];
    const int j = local % g.nj;
    const int kz = local / g.nj;

    const int lane = threadIdx.x;
    const int quad = lane >> 4, l16 = lane & 15;

    const float* pa[4];
#pragma unroll
    for (int r = 0; r < 4; ++r)
        pa[r] = g.A + (size_t)(r * 16 + l16) * g.K + kz * g.Kc + quad * 8;

    floatx4 acc[4][2] = {};
    const int steps = g.Kc >> 5;   // >= 8 and even for all uses
    short8 af[4], bfr0, bfr1;

    if (g.mode == 0) {
        const float* pb0 = g.W + (size_t)(j * 32 + l16) * g.K + kz * g.Kc + quad * 8;
        const float* pb1 = pb0 + (size_t)16 * g.K;
        float4 xa[4][2], ya[4][2];
        float4 xb[2][2], yb[2][2];
#define LOADB_NT(dst) { dst[0][0] = *(const float4*)pb0; dst[0][1] = *(const float4*)(pb0 + 4); \
        dst[1][0] = *(const float4*)pb1; dst[1][1] = *(const float4*)(pb1 + 4); \
        pb0 += 32; pb1 += 32; }
        LOADA(xa); LOADB_NT(xb);
        LOADA(ya); LOADB_NT(yb);
#pragma unroll 1
        for (int s = 0; s < steps; s += 2) {
            PACKA(xa);
            bfr0 = pack8(xb[0][0], xb[0][1]); bfr1 = pack8(xb[1][0], xb[1][1]);
            MFMA_ALL();
            if (s + 2 < steps) { LOADA(xa); LOADB_NT(xb); }
            PACKA(ya);
            bfr0 = pack8(yb[0][0], yb[0][1]); bfr1 = pack8(yb[1][0], yb[1][1]);
            MFMA_ALL();
            if (s + 3 < steps) { LOADA(ya); LOADB_NT(yb); }
        }
    } else {
        const float* pw[8];
#pragma unroll
        for (int i = 0; i < 8; ++i)
            pw[i] = g.W + ((size_t)(kz * g.Kc) + quad * 8 + i) * g.ldw + j * 32 + l16;
        const size_t ldw32 = (size_t)32 * g.ldw;
        float4 xa[4][2], ya[4][2];
        float xb[16], yb[16];
#define LOADB_NN(dst) { _Pragma("unroll") for (int i_ = 0; i_ < 8; ++i_) { \
        dst[i_] = pw[i_][0]; dst[8 + i_] = pw[i_][16]; pw[i_] += ldw32; } }
#define CVTB(src) { _Pragma("unroll") for (int e_ = 0; e_ < 8; ++e_) { \
        bfr0[e_] = (short)f2bf(src[e_]); bfr1[e_] = (short)f2bf(src[8 + e_]); } }
        LOADA(xa); LOADB_NN(xb);
        LOADA(ya); LOADB_NN(yb);
#pragma unroll 1
        for (int s = 0; s < steps; s += 2) {
            PACKA(xa);
            CVTB(xb);
            MFMA_ALL();
            if (s + 2 < steps) { LOADA(xa); LOADB_NN(xb); }
            PACKA(ya);
            CVTB(yb);
            MFMA_ALL();
            if (s + 3 < steps) { LOADA(ya); LOADB_NN(yb); }
        }
    }

#pragma unroll
    for (int r = 0; r < 4; ++r)
#pragma unroll
        for (int c = 0; c < 2; ++c) {
            const int col = j * 32 + c * 16 + l16;
            const float bj = (kz == 0) ? g.bias[col] : 0.f;
#pragma unroll
            for (int q = 0; q < 4; ++q) {
                const int row = r * 16 + quad * 4 + q;
                const float v = acc[r][c][q] + bj;
                if (g.nkz > 1) atomicAdd(&g.C[(size_t)row * g.ldc + col], v);
                else           g.C[(size_t)row * g.ldc + col] = v;
            }
        }
}

// ---------------------------------------------------------------------------
// gemm128: 128x128x32 tile for the big kv projections (NT, W f32 (N,K),
// bf16 out). 4 waves in 2x2, each 64x64 (acc 4x4). Both operands staged in
// LDS, double-buffered, one barrier per K-step, XOR swizzle (2-way, free).
// ---------------------------------------------------------------------------
struct Sub128 { const float* A; const float* W; const float* bias; unsigned short* C; int K, N, nj; };
struct Batch128 { Sub128 d[4]; int start[4]; int nd; };

__global__ __launch_bounds__(256) void gemm128(Batch128 gb)
{
    __shared__ short As[2][128 * 40];
    __shared__ short Bs[2][128 * 40];

    const int bx = blockIdx.x;
    int di = 0;
#pragma unroll 1
    for (int i = 1; i < gb.nd; ++i) if (bx >= gb.start[i]) di = i;
    const Sub128 g = gb.d[di];
    const int local = bx - gb.start[di];
    const int jb = local % g.nj, ib = local / g.nj;

    const int tid = threadIdx.x;
    const int w = tid >> 6, lane = tid & 63;
    const int quad = lane >> 4, l16 = lane & 15;
    const int wm = (w >> 1) * 64, wn = (w & 1) * 64;

    const int rS = tid >> 1;
    const int gi0 = (tid & 1) * 2;
    const int jsw = (rS >> 3) & 3;
    const int s1 = rS * 40 + ((gi0 ^ jsw) << 3);
    const int s2 = rS * 40 + (((gi0 + 1) ^ jsw) << 3);
    const float* pa = g.A + (size_t)(ib * 128 + rS) * g.K + (tid & 1) * 16;
    const float* pb = g.W + (size_t)(jb * 128 + rS) * g.K + (tid & 1) * 16;

    int aoff[4], boff[4];
#pragma unroll
    for (int r = 0; r < 4; ++r) {
        int rowA = wm + r * 16 + l16;
        aoff[r] = rowA * 40 + ((quad ^ ((rowA >> 3) & 3)) << 3);
        int rowB = wn + r * 16 + l16;
        boff[r] = rowB * 40 + ((quad ^ ((rowB >> 3) & 3)) << 3);
    }

    floatx4 acc[4][4] = {};
    float4 a0 = *(const float4*)pa,       a1 = *(const float4*)(pa + 4);
    float4 a2 = *(const float4*)(pa + 8), a3 = *(const float4*)(pa + 12);
    float4 b0 = *(const float4*)pb,       b1 = *(const float4*)(pb + 4);
    float4 b2 = *(const float4*)(pb + 8), b3 = *(const float4*)(pb + 12);
    *(short8*)&As[0][s1] = pack8(a0, a1);
    *(short8*)&As[0][s2] = pack8(a2, a3);
    *(short8*)&Bs[0][s1] = pack8(b0, b1);
    *(short8*)&Bs[0][s2] = pack8(b2, b3);
    if (g.K > 32) {
        pa += 32; pb += 32;
        a0 = *(const float4*)pa;       a1 = *(const float4*)(pa + 4);
        a2 = *(const float4*)(pa + 8); a3 = *(const float4*)(pa + 12);
        b0 = *(const float4*)pb;       b1 = *(const float4*)(pb + 4);
        b2 = *(const float4*)(pb + 8); b3 = *(const float4*)(pb + 12);
    }
    int cur = 0;
#pragma unroll 1
    for (int k0 = 0; k0 < g.K; k0 += 32) {
        __syncthreads();
        short8 af[4], bf[4];
#pragma unroll
        for (int r = 0; r < 4; ++r) {
            af[r] = *(const short8*)&As[cur][aoff[r]];
            bf[r] = *(const short8*)&Bs[cur][boff[r]];
        }
#pragma unroll
        for (int r = 0; r < 4; ++r)
#pragma unroll
            for (int c = 0; c < 4; ++c)
                acc[r][c] = __builtin_amdgcn_mfma_f32_16x16x32_bf16(af[r], bf[c], acc[r][c], 0, 0, 0);
        if (k0 + 32 < g.K) {
            short* An = As[cur ^ 1]; short* Bn = Bs[cur ^ 1];
            *(short8*)&An[s1] = pack8(a0, a1);
            *(short8*)&An[s2] = pack8(a2, a3);
            *(short8*)&Bn[s1] = pack8(b0, b1);
            *(short8*)&Bn[s2] = pack8(b2, b3);
            if (k0 + 64 < g.K) {
                pa += 32; pb += 32;
                a0 = *(const float4*)pa;       a1 = *(const float4*)(pa + 4);
                a2 = *(const float4*)(pa + 8); a3 = *(const float4*)(pa + 12);
                b0 = *(const float4*)pb;       b1 = *(const float4*)(pb + 4);
                b2 = *(const float4*)(pb + 8); b3 = *(const float4*)(pb + 12);
            }
        }
        cur ^= 1;
    }

#pragma unroll
    for (int r = 0; r < 4; ++r)
#pragma unroll
        for (int c = 0; c < 4; ++c) {
            const int col = jb * 128 + wn + c * 16 + l16;
            const float bj = g.bias[col];
#pragma unroll
            for (int q = 0; q < 4; ++q) {
                const int row = ib * 128 + wm + r * 16 + quad * 4 + q;
                g.C[(size_t)row * g.N + col] = f2bf(acc[r][c][q] + bj);
            }
        }
}

// ---------------------------------------------------------------------------
// qk_batch: S(64b x 128m tile) = 0.125 * Q_h @ K_h^T, all 28 heads batched.
// ---------------------------------------------------------------------------
__global__ __launch_bounds__(256) void qk_batch(
    const float* __restrict__ qp_t, const float* __restrict__ qp_p, const float* __restrict__ qp_c,
    const unsigned short* __restrict__ kv_t, const unsigned short* __restrict__ kv_p, const unsigned short* __restrict__ kv_c,
    float* __restrict__ S_t, float* __restrict__ S_p, float* __restrict__ S_c)
{
    __shared__ short As[64 * 72];
    __shared__ short Bs[128 * 72];
    const int hy = blockIdx.y;
    const float* qp; const unsigned short* kv; float* S; int d, h;
    if (hy < 4)       { qp = qp_t; kv = kv_t; S = S_t; d = 256;  h = hy; }
    else if (hy < 12) { qp = qp_p; kv = kv_p; S = S_p; d = 512;  h = hy - 4; }
    else              { qp = qp_c; kv = kv_c; S = S_c; d = 1024; h = hy - 12; }

    const int j0 = blockIdx.x * 128;
    const int tid = threadIdx.x;
    const int w = tid >> 6, lane = tid & 63;
    const int quad = lane >> 4, l16 = lane & 15;
    const int noff = w * 32;
    const int twoD = 2 * d;

    {
        const int b = tid >> 2, kc = (tid & 3) * 16;
        const float* ga = qp + (size_t)b * d + h * 64 + kc;
        float4 a0 = *(const float4*)(ga + 0), a1 = *(const float4*)(ga + 4);
        float4 a2 = *(const float4*)(ga + 8), a3 = *(const float4*)(ga + 12);
        *(short8*)&As[b * 72 + kc + 0] = pack8(a0, a1);
        *(short8*)&As[b * 72 + kc + 8] = pack8(a2, a3);
    }
    {
        const int m = tid >> 1, hf = (tid & 1) * 32;
        const unsigned short* gb = kv + (size_t)(j0 + m) * twoD + h * 64 + hf;
        uint4 b0 = *(const uint4*)(gb + 0),  b1 = *(const uint4*)(gb + 8);
        uint4 b2 = *(const uint4*)(gb + 16), b3 = *(const uint4*)(gb + 24);
        *(uint4*)&Bs[m * 72 + hf + 0]  = b0;
        *(uint4*)&Bs[m * 72 + hf + 8]  = b1;
        *(uint4*)&Bs[m * 72 + hf + 16] = b2;
        *(uint4*)&Bs[m * 72 + hf + 24] = b3;
    }
    __syncthreads();

    floatx4 acc[4][2] = {};
#pragma unroll
    for (int k0 = 0; k0 < 64; k0 += 32) {
        short8 af[4], bfr[2];
#pragma unroll
        for (int r = 0; r < 4; ++r)
            af[r] = *(const short8*)&As[(r * 16 + l16) * 72 + k0 + quad * 8];
#pragma unroll
        for (int c = 0; c < 2; ++c)
            bfr[c] = *(const short8*)&Bs[(noff + c * 16 + l16) * 72 + k0 + quad * 8];
#pragma unroll
        for (int r = 0; r < 4; ++r)
#pragma unroll
            for (int c = 0; c < 2; ++c)
                acc[r][c] = __builtin_amdgcn_mfma_f32_16x16x32_bf16(af[r], bfr[c], acc[r][c], 0, 0, 0);
    }
#pragma unroll
    for (int r = 0; r < 4; ++r)
#pragma unroll
        for (int c = 0; c < 2; ++c) {
            int col = j0 + noff + c * 16 + l16;
#pragma unroll
            for (int q = 0; q < 4; ++q) {
                int row = r * 16 + quad * 4 + q;
                S[((size_t)h * 64 + row) * 2048 + col] = acc[r][c][q] * 0.125f;
            }
        }
}

// ---------------------------------------------------------------------------
// softmax_p: per (head, b): softmax over the S row, written back IN PLACE
// (normalized, masked). Grid (28, 64). Block 256.
// ---------------------------------------------------------------------------
__global__ __launch_bounds__(256) void softmax_p(
    float* __restrict__ S_t, float* __restrict__ S_p, float* __restrict__ S_c,
    const uint8_t* __restrict__ mask)
{
    const int hy = blockIdx.x, b = blockIdx.y;
    float* S; int h;
    if (hy < 4)       { S = S_t; h = hy; }
    else if (hy < 12) { S = S_p; h = hy - 4; }
    else              { S = S_c; h = hy - 12; }

    const int tid = threadIdx.x;
    __shared__ __align__(16) float sc[2048];
    __shared__ float red[4];
    __shared__ float s_max, s_sum;

    float* Sr = S + ((size_t)h * 64 + b) * 2048;
    const uint8_t* mr = mask + (size_t)b * 2048;

    float lmax = -1e30f;
    for (int m = tid; m < 2048; m += 256) {
        float s = Sr[m];
        if (mr[m]) s = -1e9f;
        sc[m] = s;
        lmax = fmaxf(lmax, s);
    }
#pragma unroll
    for (int off = 32; off; off >>= 1) lmax = fmaxf(lmax, __shfl_down(lmax, off));
    if ((tid & 63) == 0) red[tid >> 6] = lmax;
    __syncthreads();
    if (tid == 0) s_max = fmaxf(fmaxf(red[0], red[1]), fmaxf(red[2], red[3]));
    __syncthreads();
    const float mx = s_max;

    float lsum = 0.f;
    for (int m = tid; m < 2048; m += 256) {
        float e = __expf(sc[m] - mx);
        sc[m] = e;
        lsum += e;
    }
#pragma unroll
    for (int off = 32; off; off >>= 1) lsum += __shfl_down(lsum, off);
    if ((tid & 63) == 0) red[tid >> 6] = lsum;
    __syncthreads();
    if (tid == 0) s_sum = red[0] + red[1] + red[2] + red[3];
    __syncthreads();
    const float inv = 1.f / s_sum;

    for (int m = tid; m < 2048; m += 256) Sr[m] = sc[m] * inv;
}

// ---------------------------------------------------------------------------
// pv_batch: O_h = P_h(64x2048) @ V_h(2048x64), MFMA, one wave per
// (head, k-chunk of 256). Grid (28, 8). atomicAdd into zeroed o_*.
// V is read from kv (bf16) directly as fragments (L2/L3-resident).
// ---------------------------------------------------------------------------
__global__ __launch_bounds__(64) void pv_batch(
    const float* __restrict__ P_t, const float* __restrict__ P_p, const float* __restrict__ P_c,
    const unsigned short* __restrict__ kv_t, const unsigned short* __restrict__ kv_p, const unsigned short* __restrict__ kv_c,
    float* __restrict__ o_t, float* __restrict__ o_p, float* __restrict__ o_c)
{
    const int hy = blockIdx.x, kz = blockIdx.y;
    const float* P; const unsigned short* kv; float* o; int d, h;
    if (hy < 4)       { P = P_t; kv = kv_t; o = o_t; d = 256;  h = hy; }
    else if (hy < 12) { P = P_p; kv = kv_p; o = o_p; d = 512;  h = hy - 4; }
    else              { P = P_c; kv = kv_c; o = o_c; d = 1024; h = hy - 12; }

    const int lane = threadIdx.x;
    const int quad = lane >> 4, l16 = lane & 15;
    const int twoD = 2 * d;

    const float* pa[4];
#pragma unroll
    for (int r = 0; r < 4; ++r)
        pa[r] = P + ((size_t)h * 64 + r * 16 + l16) * 2048 + kz * 256 + quad * 8;
    const unsigned short* pb = kv + (size_t)(kz * 256 + quad * 8) * twoD + d + h * 64 + l16;

    floatx4 acc[4][4] = {};
#pragma unroll 1
    for (int s = 0; s < 8; ++s) {
        short8 af[4];
#pragma unroll
        for (int r = 0; r < 4; ++r) {
            float4 a0 = *(const float4*)pa[r], a1 = *(const float4*)(pa[r] + 4);
            af[r] = pack8(a0, a1);
            pa[r] += 32;
        }
        short8 bf[4];
#pragma unroll
        for (int c = 0; c < 4; ++c)
#pragma unroll
            for (int i = 0; i < 8; ++i)
                bf[c][i] = (short)pb[(size_t)i * twoD + c * 16];
        pb += (size_t)32 * twoD;
#pragma unroll
        for (int r = 0; r < 4; ++r)
#pragma unroll
            for (int c = 0; c < 4; ++c)
                acc[r][c] = __builtin_amdgcn_mfma_f32_16x16x32_bf16(af[r], bf[c], acc[r][c], 0, 0, 0);
    }
#pragma unroll
    for (int r = 0; r < 4; ++r)
#pragma unroll
        for (int c = 0; c < 4; ++c)
#pragma unroll
            for (int q = 0; q < 4; ++q) {
                const int row = r * 16 + quad * 4 + q;
                atomicAdd(&o[(size_t)row * d + h * 64 + c * 16 + l16], acc[r][c][q]);
            }
}

// ---------------------------------------------------------------------------
__global__ __launch_bounds__(256) void ln_kernel(
    float* __restrict__ x, const float* __restrict__ g, const float* __restrict__ bb)
{
    const int row = blockIdx.x;
    float* xr = x + (size_t)row * 4096;
    const int tid = threadIdx.x;
    float v[16];
    float sum = 0.f, sumsq = 0.f;
#pragma unroll
    for (int i = 0; i < 16; ++i) {
        v[i] = xr[tid + i * 256];
        sum += v[i];
        sumsq += v[i] * v[i];
    }
    __shared__ float rs[4], rq[4];
#pragma unroll
    for (int off = 32; off; off >>= 1) {
        sum += __shfl_down(sum, off);
        sumsq += __shfl_down(sumsq, off);
    }
    if ((tid & 63) == 0) { rs[tid >> 6] = sum; rq[tid >> 6] = sumsq; }
    __syncthreads();
    const float ts = rs[0] + rs[1] + rs[2] + rs[3];
    const float tq = rq[0] + rq[1] + rq[2] + rq[3];
    const float mu = ts * (1.f / 4096.f);
    const float var = tq * (1.f / 4096.f) - mu * mu;
    const float r = rsqrtf(var + 1e-5f);
#pragma unroll
    for (int i = 0; i < 16; ++i) {
        int e = tid + i * 256;
        xr[e] = (v[i] - mu) * r * g[e] + bb[e];
    }
}

// ---------------------------------------------------------------------------
static void addw(WaveBatch& G, int& tot,
                 const float* A, const float* W, const float* bias, float* C,
                 int K, int Kc, int ldw, int ldc, int nj, int nkz, int mode)
{
    WaveG& s = G.d[G.nd];
    s.A = A; s.W = W; s.bias = bias; s.C = C;
    s.K = K; s.Kc = Kc; s.ldw = ldw; s.ldc = ldc; s.nj = nj; s.nkz = nkz; s.mode = mode;
    G.start[G.nd] = tot;
    tot += nj * nkz;
    G.nd++;
}
static void add128(Batch128& G, int& tot,
                   const float* A, const float* W, const float* bias, unsigned short* C,
                   int K, int N, int nj, int ni)
{
    Sub128& s = G.d[G.nd];
    s.A = A; s.W = W; s.bias = bias; s.C = C; s.K = K; s.N = N; s.nj = nj;
    G.start[G.nd] = tot;
    tot += nj * ni;
    G.nd++;
}

extern "C" void kernel_launch(void* const* d_in, const int* in_sizes, int n_in,
                              void* d_out, int out_size, void* d_ws, size_t ws_size,
                              hipStream_t stream)
{
    const float*   hs     = (const float*)d_in[0];
    const float*   fib_t  = (const float*)d_in[1];
    const float*   fib_p  = (const float*)d_in[2];
    const float*   fib_c  = (const float*)d_in[3];
    const uint8_t* mask   = (const uint8_t*)d_in[4];
    const float* Wq_t   = (const float*)d_in[5];  const float* bq_t   = (const float*)d_in[6];
    const float* Wq_p   = (const float*)d_in[7];  const float* bq_p   = (const float*)d_in[8];
    const float* Wq_c   = (const float*)d_in[9];  const float* bq_c   = (const float*)d_in[10];
    const float* Wqkv_t = (const float*)d_in[11]; const float* bqkv_t = (const float*)d_in[12];
    const float* Wo_t   = (const float*)d_in[13]; const float* bo_t   = (const float*)d_in[14];
    const float* Wqkv_p = (const float*)d_in[15]; const float* bqkv_p = (const float*)d_in[16];
    const float* Wo_p   = (const float*)d_in[17]; const float* bo_p   = (const float*)d_in[18];
    const float* Wqkv_c = (const float*)d_in[19]; const float* bqkv_c = (const float*)d_in[20];
    const float* Wo_c   = (const float*)d_in[21]; const float* bo_c   = (const float*)d_in[22];
    const float* Wl_t   = (const float*)d_in[23]; const float* bl_t   = (const float*)d_in[24];
    const float* Wl_p   = (const float*)d_in[25]; const float* bl_p   = (const float*)d_in[26];
    const float* Wl_c   = (const float*)d_in[27]; const float* bl_c   = (const float*)d_in[28];
    const float* ln_g   = (const float*)d_in[29]; const float* ln_b   = (const float*)d_in[30];

    char* wsb = (char*)d_ws;
    // zeroed region: split-K atomic destinations
    float* q_t  = (float*)wsb; wsb += 64 * 256 * 4;
    float* q_p  = (float*)wsb; wsb += 64 * 512 * 4;
    float* q_c  = (float*)wsb; wsb += 64 * 1024 * 4;
    float* qp_t = (float*)wsb; wsb += 64 * 256 * 4;
    float* qp_p = (float*)wsb; wsb += 64 * 512 * 4;
    float* qp_c = (float*)wsb; wsb += 64 * 1024 * 4;
    float* po_t = (float*)wsb; wsb += 64 * 256 * 4;
    float* po_p = (float*)wsb; wsb += 64 * 512 * 4;
    float* po_c = (float*)wsb; wsb += 64 * 1024 * 4;
    float* o_t  = (float*)wsb; wsb += 64 * 256 * 4;
    float* o_p  = (float*)wsb; wsb += 64 * 512 * 4;
    float* o_c  = (float*)wsb; wsb += 64 * 1024 * 4;
    size_t zbytes = (size_t)(wsb - (char*)d_ws);
    unsigned short* kv_t = (unsigned short*)wsb; wsb += 2048 * 512 * 2;
    unsigned short* kv_p = (unsigned short*)wsb; wsb += 2048 * 1024 * 2;
    unsigned short* kv_c = (unsigned short*)wsb; wsb += 2048 * 2048 * 2;
    float* S_t = (float*)wsb; wsb += (size_t)4  * 64 * 2048 * 4;
    float* S_p = (float*)wsb; wsb += (size_t)8  * 64 * 2048 * 4;
    float* S_c = (float*)wsb; wsb += (size_t)16 * 64 * 2048 * 4;
    float* out = (float*)d_out;

    hipMemsetAsync(d_ws, 0, zbytes, stream);

    // ---- launch 1: bundle query heads (NT, split-K 16)
    {
        WaveBatch G{}; int tot = 0; G.nd = 0;
        addw(G, tot, hs, Wq_c, bq_c, q_c, 4096, 256, 0, 1024, 32, 16, 0);
        addw(G, tot, hs, Wq_p, bq_p, q_p, 4096, 256, 0, 512,  16, 16, 0);
        addw(G, tot, hs, Wq_t, bq_t, q_t, 4096, 256, 0, 256,  8,  16, 0);
        wave_gemm<<<dim3(tot), dim3(64), 0, stream>>>(G);
    }

    // ---- launch 2: kv projections, 128x128 tile (bf16 out)
    {
        Batch128 G{}; int tot = 0; G.nd = 0;
        add128(G, tot, fib_c, Wqkv_c + 1024 * 1024, bqkv_c + 1024, kv_c, 1024, 2048, 16, 16);
        add128(G, tot, fib_p, Wqkv_p + 512 * 512,   bqkv_p + 512,  kv_p, 512,  1024, 8,  16);
        add128(G, tot, fib_t, Wqkv_t + 256 * 256,   bqkv_t + 256,  kv_t, 256,  512,  4,  16);
        gemm128<<<dim3(tot), dim3(256), 0, stream>>>(G);
    }

    // ---- launch 3: q in-proj (NT)
    {
        WaveBatch G{}; int tot = 0; G.nd = 0;
        addw(G, tot, q_c, Wqkv_c, bqkv_c, qp_c, 1024, 256, 0, 1024, 32, 4, 0);
        addw(G, tot, q_p, Wqkv_p, bqkv_p, qp_p, 512,  256, 0, 512,  16, 2, 0);
        addw(G, tot, q_t, Wqkv_t, bqkv_t, qp_t, 256,  256, 0, 256,  8,  1, 0);
        wave_gemm<<<dim3(tot), dim3(64), 0, stream>>>(G);
    }

    // ---- launch 4/5/6: attention
    qk_batch<<<dim3(16, 28), dim3(256), 0, stream>>>(qp_t, qp_p, qp_c, kv_t, kv_p, kv_c, S_t, S_p, S_c);
    softmax_p<<<dim3(28, 64), dim3(256), 0, stream>>>(S_t, S_p, S_c, mask);
    pv_batch<<<dim3(28, 8), dim3(64), 0, stream>>>(S_t, S_p, S_c, kv_t, kv_p, kv_c, o_t, o_p, o_c);

    // ---- launch 7: out-proj (NT)
    {
        WaveBatch G{}; int tot = 0; G.nd = 0;
        addw(G, tot, o_c, Wo_c, bo_c, po_c, 1024, 256, 0, 1024, 32, 4, 0);
        addw(G, tot, o_p, Wo_p, bo_p, po_p, 512,  256, 0, 512,  16, 2, 0);
        addw(G, tot, o_t, Wo_t, bo_t, po_t, 256,  256, 0, 256,  8,  1, 0);
        wave_gemm<<<dim3(tot), dim3(64), 0, stream>>>(G);
    }

    // ---- launch 8: lifts (NN, nkz=1, bias folded, direct store)
    {
        WaveBatch G{}; int tot = 0; G.nd = 0;
        for (int z = 0; z < 4; ++z)
            addw(G, tot, po_c, Wl_c + (size_t)z * 1024 * 4096, bl_c + z * 4096,
                 out + (size_t)(12 + z) * 4096, 1024, 1024, 4096, 16 * 4096, 128, 1, 1);
        for (int z = 0; z < 8; ++z)
            addw(G, tot, po_p, Wl_p + (size_t)z * 512 * 4096, bl_p + z * 4096,
                 out + (size_t)(4 + z) * 4096, 512, 512, 4096, 16 * 4096, 128, 1, 1);
        for (int z = 0; z < 4; ++z)
            addw(G, tot, po_t, Wl_t + (size_t)z * 256 * 4096, bl_t + z * 4096,
                 out + (size_t)z * 4096, 256, 256, 4096, 16 * 4096, 128, 1, 1);
        wave_gemm<<<dim3(tot), dim3(64), 0, stream>>>(G);
    }

    // ---- launch 9: layernorm in place
    ln_kernel<<<dim3(1024), dim3(256), 0, stream>>>(out, ln_g, ln_b);
}